// Round 5
// baseline (297.937 us; speedup 1.0000x reference)
//
#include <hip/hip_runtime.h>

namespace {

constexpr int Ldim = 6400;   // rows (h0*w0)
constexpr int Sdim = 6400;   // cols (h1*w1)
constexpr float INV_CT = 0.0390625f;  // 1/(256*0.1), exact
constexpr float THR = 0.2f;
constexpr int CAP = 65536;   // candidate capacity; provable bound ~32K (sum conf<=1/row)

typedef __attribute__((ext_vector_type(8))) short short8;
typedef __attribute__((ext_vector_type(4))) float f32x4;

__device__ __forceinline__ void atomicMaxPosF(float* addr, float v) {
  // valid for non-negative floats: uint bit order == float order
  atomicMax(reinterpret_cast<unsigned int*>(addr), __float_as_uint(v));
}

__device__ __forceinline__ bool valid80(int idx) {
  const int i = idx / 80;
  const int j = idx - i * 80;
  return (i >= 2) & (i < 78) & (j >= 2) & (j < 78);
}

// round-to-nearest-even fp32 -> bf16 bits
__device__ __forceinline__ unsigned short f2bf(float v) {
  unsigned u = __float_as_uint(v);
  return (unsigned short)((u + 0x7fffu + ((u >> 16) & 1u)) >> 16);
}

// The ONE conf expression (candidates, RM/CM, scatter all use values produced
// by this in pass B -> == tests bitwise-consistent by construction).
__device__ __forceinline__ float conf1(float s, float rs, float cs) {
  return expf(2.f * s) / (rs * cs);
}
// The ONE candidate precheck (over-inclusive by 0.05 in log domain:
// catches every element with conf > 0.2*e^-0.05 ~= 0.19).
__device__ __forceinline__ bool precand(float s, float lc, float cu) {
  return 2.f * s - lc > cu;
}

typedef const __attribute__((address_space(1))) unsigned int guint;
typedef __attribute__((address_space(3))) unsigned int suint;
__device__ __forceinline__ void gload16(const void* g, void* l) {
  __builtin_amdgcn_global_load_lds((guint*)g, (suint*)l, 16, 0, 0);
}

// --- P-layout (unchanged from R3/R4; measured 0 bank conflicts) -------------
// X' = [kstep 0..7][row 0..6399][granule g' 0..3][8 bf16]  (row block = 64 B)
// slot g' of row r holds k-granule g' ^ ((r>>1)&3).  Staging of a 256-row
// span is a contiguous 16 KB copy; frag ds_read_b128 is 2-way/free.

__global__ __launch_bounds__(256)
void k_split(const float* __restrict__ X, unsigned short* __restrict__ Xh) {
  const int g = blockIdx.x * 256 + threadIdx.x;  // 6400*32 = 204800
  const int r = g >> 5;
  const int gt = g & 31;
  const float* src = X + ((size_t)r << 8) + (gt << 3);
  const float4 a = *reinterpret_cast<const float4*>(src);
  const float4 b = *reinterpret_cast<const float4*>(src + 4);
  short8 hv;
  hv[0] = (short)f2bf(a.x); hv[1] = (short)f2bf(a.y);
  hv[2] = (short)f2bf(a.z); hv[3] = (short)f2bf(a.w);
  hv[4] = (short)f2bf(b.x); hv[5] = (short)f2bf(b.y);
  hv[6] = (short)f2bf(b.z); hv[7] = (short)f2bf(b.w);
  const int gp = (gt & 3) ^ ((r >> 1) & 3);
  const size_t dst = ((size_t)((gt >> 2) * Ldim + r) * 4 + gp) << 3;
  *reinterpret_cast<short8*>(Xh + dst) = hv;
}

// --- shared GEMM main loop: 256x256 tile, BK=32, 8 waves (2x4 -> 128x64 per
//     wave), double-buffered LDS, stage-next-before-compute (2-phase).
__device__ __forceinline__ void gemm256(
    const unsigned short* __restrict__ A, const unsigned short* __restrict__ B,
    int m0, int n0, int tid,
    unsigned short (*sA)[8192], unsigned short (*sB)[8192], f32x4 acc[8][4]) {
  const int lane = tid & 63;
  const int wave = tid >> 6;        // 0..7
  const int wr = wave >> 2;         // 0..1 (row half)
  const int wc = wave & 3;          // 0..3 (col quarter)
  const int ll = lane & 15;         // frag row/col
  const int lg = lane >> 4;         // frag k-group

#pragma unroll
  for (int mi = 0; mi < 8; ++mi)
#pragma unroll
    for (int ni = 0; ni < 4; ++ni) acc[mi][ni] = (f32x4){0.f, 0.f, 0.f, 0.f};

  // stage one k-tile: A rows m0..m0+255 and B rows n0..n0+255 are each a
  // CONTIGUOUS 16 KB block in P-layout -> 2+2 gload16/thread, linear LDS.
  // LDS arg must be wave-uniform (HW adds lane*16); global arg is per-lane.
  auto stage = [&](int slot, int ks) {
    const size_t kb = (size_t)ks * (Ldim * 32);
    const unsigned short* Abase = A + kb + (size_t)m0 * 32;
    const unsigned short* Bbase = B + kb + (size_t)n0 * 32;
    gload16(Abase + (size_t)tid * 8,         &sA[slot][wave * 512]);
    gload16(Abase + (size_t)(tid + 512) * 8, &sA[slot][wave * 512 + 4096]);
    gload16(Bbase + (size_t)tid * 8,         &sB[slot][wave * 512]);
    gload16(Bbase + (size_t)(tid + 512) * 8, &sB[slot][wave * 512 + 4096]);
  };

  stage(0, 0);
  __syncthreads();  // compiler drains vmcnt before s_barrier

  for (int ks = 0; ks < 8; ++ks) {
    const int cur = ks & 1;
    if (ks < 7) stage(cur ^ 1, ks + 1);  // prefetch overlaps this tile's MFMA

    auto rd = [&](unsigned short* S, int row) -> short8 {
      const int gp = lg ^ ((row >> 1) & 3);  // inverse granule swizzle
      return *reinterpret_cast<const short8*>(&S[(row * 4 + gp) * 8]);
    };
    short8 af[8], bfv[4];
#pragma unroll
    for (int mi = 0; mi < 8; ++mi) af[mi] = rd(sA[cur], wr * 128 + mi * 16 + ll);
#pragma unroll
    for (int ni = 0; ni < 4; ++ni) bfv[ni] = rd(sB[cur], wc * 64 + ni * 16 + ll);
#pragma unroll
    for (int mi = 0; mi < 8; ++mi)
#pragma unroll
      for (int ni = 0; ni < 4; ++ni)
        acc[mi][ni] = __builtin_amdgcn_mfma_f32_16x16x32_bf16(af[mi], bfv[ni], acc[mi][ni], 0, 0, 0);

    __syncthreads();  // drains prefetch vmcnt + lgkm before buffer swap
  }

#pragma unroll
  for (int mi = 0; mi < 8; ++mi)
#pragma unroll
    for (int ni = 0; ni < 4; ++ni) acc[mi][ni] *= INV_CT;
}

// --- Pass A: exp-sum stats only (no sim write).
__global__ __launch_bounds__(512, 2)
void k_gemm_stats(const unsigned short* __restrict__ A, const unsigned short* __restrict__ B,
                  float* __restrict__ Rsum, float* __restrict__ Csum) {
  __shared__ unsigned short sA[2][8192], sB[2][8192];
  const int tid = threadIdx.x;
  const int lane = tid & 63, wave = tid >> 6;
  const int wr = wave >> 2, wc = wave & 3;
  const int ll = lane & 15, lg = lane >> 4;
  const int bx = blockIdx.x % (Sdim / 256);
  const int by = blockIdx.x / (Sdim / 256);
  const int m0 = by * 256, n0 = bx * 256;

  f32x4 acc[8][4];
  gemm256(A, B, m0, n0, tid, sA, sB, acc);

  // C/D layout: col = lane&15, row = (lane>>4)*4 + reg  [m89/m91]
  float colp[4] = {0.f, 0.f, 0.f, 0.f};
#pragma unroll
  for (int mi = 0; mi < 8; ++mi)
#pragma unroll
    for (int r = 0; r < 4; ++r) {
      float re = 0.f;
#pragma unroll
      for (int ni = 0; ni < 4; ++ni) {
        const float e = expf(acc[mi][ni][r]);
        re += e;
        colp[ni] += e;
      }
      re += __shfl_xor(re, 1);
      re += __shfl_xor(re, 2);
      re += __shfl_xor(re, 4);
      re += __shfl_xor(re, 8);
      if (ll == 0)
        atomicAdd(&Rsum[m0 + wr * 128 + mi * 16 + lg * 4 + r], re);
    }
#pragma unroll
  for (int ni = 0; ni < 4; ++ni) {
    float c = colp[ni];
    c += __shfl_xor(c, 16);
    c += __shfl_xor(c, 32);
    if (lane < 16) atomicAdd(&Csum[n0 + wc * 64 + ni * 16 + lane], c);
  }
}

// --- k_logs: lnC[s] = log(Csum), cut[l] = log(Rsum) + ln(0.2) - slack
__global__ __launch_bounds__(256)
void k_logs(const float* __restrict__ Rsum, const float* __restrict__ Csum,
            float* __restrict__ lnC, float* __restrict__ cut) {
  const int i = blockIdx.x * 256 + threadIdx.x;  // 6400
  lnC[i] = logf(Csum[i]);
  cut[i] = logf(Rsum[i]) + logf(THR) - 0.05f;
}

// --- Pass B: recompute sim in-register, extract candidates (conf >~ 0.19),
//     update RM/CM maxes and append to compacted candidate list.
//     Exact where it matters: a row/col whose max conf < 0.19 can contribute
//     no output; otherwise its max IS a candidate and RM/CM are exact.
__global__ __launch_bounds__(512, 2)
void k_gemm_cand(const unsigned short* __restrict__ A, const unsigned short* __restrict__ B,
                 const float* __restrict__ Rsum, const float* __restrict__ Csum,
                 const float* __restrict__ lnC, const float* __restrict__ cut,
                 float* __restrict__ RM, float* __restrict__ CM,
                 unsigned int* __restrict__ cnt, unsigned int* __restrict__ cidx,
                 float* __restrict__ cconf) {
  __shared__ unsigned short sA[2][8192], sB[2][8192];
  const int tid = threadIdx.x;
  const int lane = tid & 63, wave = tid >> 6;
  const int wr = wave >> 2, wc = wave & 3;
  const int ll = lane & 15, lg = lane >> 4;
  const int bx = blockIdx.x % (Sdim / 256);
  const int by = blockIdx.x / (Sdim / 256);
  const int m0 = by * 256, n0 = bx * 256;

  f32x4 acc[8][4];
  gemm256(A, B, m0, n0, tid, sA, sB, acc);

  float lc[4];
#pragma unroll
  for (int ni = 0; ni < 4; ++ni) lc[ni] = lnC[n0 + wc * 64 + ni * 16 + ll];

#pragma unroll
  for (int mi = 0; mi < 8; ++mi)
#pragma unroll
    for (int r = 0; r < 4; ++r) {
      const int row = m0 + wr * 128 + mi * 16 + lg * 4 + r;
      const float cu = cut[row];
      const bool b0 = precand(acc[mi][0][r], lc[0], cu);
      const bool b1 = precand(acc[mi][1][r], lc[1], cu);
      const bool b2 = precand(acc[mi][2][r], lc[2], cu);
      const bool b3 = precand(acc[mi][3][r], lc[3], cu);
      if (b0 | b1 | b2 | b3) {  // rare path
        const float rs = Rsum[row];
#pragma unroll
        for (int ni = 0; ni < 4; ++ni) {
          const bool b = (ni == 0) ? b0 : (ni == 1) ? b1 : (ni == 2) ? b2 : b3;
          if (b) {
            const int col = n0 + wc * 64 + ni * 16 + ll;
            const float c = conf1(acc[mi][ni][r], rs, Csum[col]);
            atomicMaxPosF(&RM[row], c);
            atomicMaxPosF(&CM[col], c);
            const unsigned t = atomicAdd(cnt, 1u);
            if (t < CAP) {
              cidx[t] = (unsigned)row * Sdim + col;
              cconf[t] = c;
            }
          }
        }
      }
    }
}

// --- k_scatter: final mask over the (tiny) candidate list; writes matches.
__global__ __launch_bounds__(256)
void k_scatter(const unsigned int* __restrict__ cnt, const unsigned int* __restrict__ cidx,
               const float* __restrict__ cconf, const float* __restrict__ RM,
               const float* __restrict__ CM, float* __restrict__ out) {
  const int n = (int)min(*cnt, (unsigned)CAP);
  for (int i = blockIdx.x * 256 + threadIdx.x; i < n; i += gridDim.x * 256) {
    const unsigned idx = cidx[i];
    const int l = idx / Sdim;
    const int s = idx - l * Sdim;
    const float c = cconf[i];
    if (c > THR && valid80(l) && valid80(s) && c == RM[l] && c == CM[s])
      out[idx] = c;
  }
}

}  // namespace

extern "C" void kernel_launch(void* const* d_in, const int* in_sizes, int n_in,
                              void* d_out, int out_size, void* d_ws, size_t ws_size,
                              hipStream_t stream) {
  (void)in_sizes; (void)n_in; (void)out_size; (void)ws_size;
  const float* x0 = reinterpret_cast<const float*>(d_in[0]);
  const float* x1 = reinterpret_cast<const float*>(d_in[1]);
  float* out = reinterpret_cast<float*>(d_out);

  // ws layout: [Rsum 6400][Csum 6400][RM 6400][CM 6400][cnt 4][lnC 6400]
  //            [cut 6400][cidx CAP][cconf CAP][XA][XB]
  float* Rsum = reinterpret_cast<float*>(d_ws);
  float* Csum = Rsum + Ldim;
  float* RM = Csum + Sdim;
  float* CM = RM + Ldim;
  unsigned int* cnt = reinterpret_cast<unsigned int*>(CM + Sdim);
  float* lnC = reinterpret_cast<float*>(cnt + 4);
  float* cut = lnC + Sdim;
  unsigned int* cidx = reinterpret_cast<unsigned int*>(cut + Ldim);
  float* cconf = reinterpret_cast<float*>(cidx + CAP);
  unsigned short* XA = reinterpret_cast<unsigned short*>(cconf + CAP);
  const size_t PSZ = (size_t)8 * Ldim * 32;  // ushorts per pre-split buffer
  unsigned short* XB = XA + PSZ;

  // zero stats + count (sums -> 0; RM/CM of positive floats -> 0)
  hipMemsetAsync(d_ws, 0, sizeof(float) * (size_t)(4 * Ldim) + 16, stream);

  k_split<<<Ldim * 32 / 256, 256, 0, stream>>>(x0, XA);
  k_split<<<Ldim * 32 / 256, 256, 0, stream>>>(x1, XB);
  k_gemm_stats<<<(Ldim / 256) * (Sdim / 256), 512, 0, stream>>>(XA, XB, Rsum, Csum);
  k_logs<<<Ldim / 256, 256, 0, stream>>>(Rsum, Csum, lnC, cut);
  k_gemm_cand<<<(Ldim / 256) * (Sdim / 256), 512, 0, stream>>>(
      XA, XB, Rsum, Csum, lnC, cut, RM, CM, cnt, cidx, cconf);
  hipMemsetAsync(out, 0, sizeof(float) * (size_t)Ldim * Sdim, stream);
  k_scatter<<<64, 256, 0, stream>>>(cnt, cidx, cconf, RM, CM, out);
}

// Round 6
// 274.721 us; speedup vs baseline: 1.0845x; 1.0845x over previous
//
#include <hip/hip_runtime.h>

namespace {

constexpr int Ldim = 6400;   // rows (h0*w0)
constexpr int Sdim = 6400;   // cols (h1*w1)
constexpr float INV_CT = 0.0390625f;  // 1/(256*0.1), exact
constexpr float THR = 0.2f;
constexpr int CAP = 65536;   // candidate capacity (expected ~0 for this data)

typedef __attribute__((ext_vector_type(8))) short short8;
typedef __attribute__((ext_vector_type(4))) float f32x4;

__device__ __forceinline__ void atomicMaxPosF(float* addr, float v) {
  // valid for non-negative floats: uint bit order == float order
  atomicMax(reinterpret_cast<unsigned int*>(addr), __float_as_uint(v));
}

__device__ __forceinline__ bool valid80(int idx) {
  const int i = idx / 80;
  const int j = idx - i * 80;
  return (i >= 2) & (i < 78) & (j >= 2) & (j < 78);
}

// round-to-nearest-even fp32 -> bf16 bits
__device__ __forceinline__ unsigned short f2bf(float v) {
  unsigned u = __float_as_uint(v);
  return (unsigned short)((u + 0x7fffu + ((u >> 16) & 1u)) >> 16);
}

// The ONE conf expression. Computed exactly once per candidate (k_final1);
// k_final2 reuses the stored value -> == tests bitwise-consistent.
__device__ __forceinline__ float conf1(float s, float rs, float cs) {
  return expf(2.f * s) / (rs * cs);
}

typedef const __attribute__((address_space(1))) unsigned int guint;
typedef __attribute__((address_space(3))) unsigned int suint;
__device__ __forceinline__ void gload16(const void* g, void* l) {
  __builtin_amdgcn_global_load_lds((guint*)g, (suint*)l, 16, 0, 0);
}

// --- P-layout (R3/R4-verified: 0 bank conflicts) ----------------------------
// X' = [kstep 0..7][row 0..6399][granule g' 0..3][8 bf16]  (row block = 64 B)
// slot g' of row r holds k-granule g' ^ ((r>>1)&3).

__global__ __launch_bounds__(256)
void k_split(const float* __restrict__ X, unsigned short* __restrict__ Xh) {
  const int g = blockIdx.x * 256 + threadIdx.x;  // 6400*32 = 204800
  const int r = g >> 5;
  const int gt = g & 31;
  const float* src = X + ((size_t)r << 8) + (gt << 3);
  const float4 a = *reinterpret_cast<const float4*>(src);
  const float4 b = *reinterpret_cast<const float4*>(src + 4);
  short8 hv;
  hv[0] = (short)f2bf(a.x); hv[1] = (short)f2bf(a.y);
  hv[2] = (short)f2bf(a.z); hv[3] = (short)f2bf(a.w);
  hv[4] = (short)f2bf(b.x); hv[5] = (short)f2bf(b.y);
  hv[6] = (short)f2bf(b.z); hv[7] = (short)f2bf(b.w);
  const int gp = (gt & 3) ^ ((r >> 1) & 3);
  const size_t dst = ((size_t)((gt >> 2) * Ldim + r) * 4 + gp) << 3;
  *reinterpret_cast<short8*>(Xh + dst) = hv;
}

// --- GEMM main loop (verbatim R4 structure: 128x128, BK=32, 4 waves,
//     double-buffered LDS, 2-phase stage-before-compute).
__device__ __forceinline__ void gemm128(
    const unsigned short* __restrict__ A, const unsigned short* __restrict__ B,
    int m0, int n0, int wave, int lane,
    unsigned short (*sA)[4096], unsigned short (*sB)[4096], f32x4 acc[4][4]) {
  const int wr = wave >> 1, wc = wave & 1;
  const int ll = lane & 15;
  const int lg = lane >> 4;
  const int arow = lane >> 2;
  const int gsel = (lane & 3) * 8;

#pragma unroll
  for (int mi = 0; mi < 4; ++mi)
#pragma unroll
    for (int ni = 0; ni < 4; ++ni) acc[mi][ni] = (f32x4){0.f, 0.f, 0.f, 0.f};

  auto stage = [&](int slot, int ks) {
    const size_t kb = (size_t)ks * (Ldim * 32);
#pragma unroll
    for (int p = 0; p < 2; ++p) {
      const int ch = wave * 2 + p;
      const size_t asrc = kb + (size_t)(m0 + ch * 16 + arow) * 32 + gsel;
      const size_t bsrc = kb + (size_t)(n0 + ch * 16 + arow) * 32 + gsel;
      gload16(A + asrc, &sA[slot][ch * 512]);
      gload16(B + bsrc, &sB[slot][ch * 512]);
    }
  };

  stage(0, 0);
  __syncthreads();  // compiler drains vmcnt before s_barrier

  for (int ks = 0; ks < 8; ++ks) {
    const int cur = ks & 1;
    if (ks < 7) stage(cur ^ 1, ks + 1);  // prefetch overlaps this tile's MFMA

    auto rd = [&](unsigned short* S, int row) -> short8 {
      const int gp = lg ^ ((row >> 1) & 3);  // inverse granule swizzle
      return *reinterpret_cast<const short8*>(&S[(row * 4 + gp) * 8]);
    };
    short8 af[4], bfv[4];
#pragma unroll
    for (int mi = 0; mi < 4; ++mi) af[mi] = rd(sA[cur], wr * 64 + mi * 16 + ll);
#pragma unroll
    for (int ni = 0; ni < 4; ++ni) bfv[ni] = rd(sB[cur], wc * 64 + ni * 16 + ll);
#pragma unroll
    for (int mi = 0; mi < 4; ++mi)
#pragma unroll
      for (int ni = 0; ni < 4; ++ni)
        acc[mi][ni] = __builtin_amdgcn_mfma_f32_16x16x32_bf16(af[mi], bfv[ni], acc[mi][ni], 0, 0, 0);

    __syncthreads();  // drains prefetch vmcnt + lgkm before buffer swap
  }

#pragma unroll
  for (int mi = 0; mi < 4; ++mi)
#pragma unroll
    for (int ni = 0; ni < 4; ++ni) acc[mi][ni] *= INV_CT;
}

// --- THE single GEMM pass: exp-sum stats + bound-precheck candidate extract.
// Precheck uses tile-local LOWER bounds Rlow (row sum over this wave's 64
// cols) and Clow (col sum over its 64 rows): element passes iff
//   s > 0.5*(ln(0.18) + ln(Rlow) + ln(Clow))   i.e.  e^{2s} > 0.18*Rlow*Clow.
// Over-inclusive for conf>0.2 since Rlow<=Rsum, Clow<=Csum and 0.18<0.2
// (11% slack >> fp rounding). A row/col whose true max is not a candidate
// has all conf < 0.2 there -> RM/CM value irrelevant for it.
__global__ __launch_bounds__(256)
void k_gemm_all(const unsigned short* __restrict__ A, const unsigned short* __restrict__ B,
                float* __restrict__ Rsum, float* __restrict__ Csum,
                unsigned int* __restrict__ cnt, unsigned int* __restrict__ cidx,
                float* __restrict__ csim) {
  __shared__ unsigned short sA[2][4096], sB[2][4096];
  const int tid = threadIdx.x;
  const int lane = tid & 63, wave = tid >> 6;
  const int wr = wave >> 1, wc = wave & 1;
  const int ll = lane & 15, lg = lane >> 4;
  const int bx = blockIdx.x % (Sdim / 128);
  const int by = blockIdx.x / (Sdim / 128);
  const int m0 = by * 128, n0 = bx * 128;

  f32x4 acc[4][4];
  gemm128(A, B, m0, n0, wave, lane, sA, sB, acc);

  // C/D layout: col = lane&15, row = (lane>>4)*4 + reg  [m89/m91]
  // loop1: exp sums -> atomics; keep per-(mi,r) row sums and per-col sums.
  float re[16];
  float colp[4] = {0.f, 0.f, 0.f, 0.f};
#pragma unroll
  for (int mi = 0; mi < 4; ++mi)
#pragma unroll
    for (int r = 0; r < 4; ++r) {
      float s = 0.f;
#pragma unroll
      for (int ni = 0; ni < 4; ++ni) {
        const float e = expf(acc[mi][ni][r]);
        s += e;
        colp[ni] += e;
      }
      s += __shfl_xor(s, 1);
      s += __shfl_xor(s, 2);
      s += __shfl_xor(s, 4);
      s += __shfl_xor(s, 8);
      re[mi * 4 + r] = s;  // row sum over this wave's 64 cols (all 16 lanes)
      if (ll == 0)
        atomicAdd(&Rsum[m0 + wr * 64 + mi * 16 + lg * 4 + r], s);
    }
  float clw[4];
#pragma unroll
  for (int ni = 0; ni < 4; ++ni) {
    float c = colp[ni];
    c += __shfl_xor(c, 16);
    c += __shfl_xor(c, 32);
    clw[ni] = c;  // col sum over this wave's 64 rows (col = ni*16 + ll)
    if (lane < 16) atomicAdd(&Csum[n0 + wc * 64 + ni * 16 + lane], c);
  }

  // loop2: log-domain precheck, emit candidates (rare).
  constexpr float L018 = -1.7147984f;  // ln(0.18)
  float lc[4];
#pragma unroll
  for (int ni = 0; ni < 4; ++ni) lc[ni] = 0.5f * logf(clw[ni]);
#pragma unroll
  for (int mi = 0; mi < 4; ++mi)
#pragma unroll
    for (int r = 0; r < 4; ++r) {
      const float tr = 0.5f * (L018 + logf(re[mi * 4 + r]));
#pragma unroll
      for (int ni = 0; ni < 4; ++ni) {
        if (acc[mi][ni][r] > tr + lc[ni]) {
          const int row = m0 + wr * 64 + mi * 16 + lg * 4 + r;
          const int col = n0 + wc * 64 + ni * 16 + ll;
          const unsigned t = atomicAdd(cnt, 1u);
          if (t < CAP) {
            cidx[t] = (unsigned)row * Sdim + col;
            csim[t] = acc[mi][ni][r];
          }
        }
      }
    }
}

// --- k_final1: exact conf for each candidate (stored), RM/CM atomicMax.
__global__ __launch_bounds__(256)
void k_final1(const unsigned int* __restrict__ cnt, const unsigned int* __restrict__ cidx,
              const float* __restrict__ csim, const float* __restrict__ Rsum,
              const float* __restrict__ Csum, float* __restrict__ RM,
              float* __restrict__ CM, float* __restrict__ cconf) {
  const int n = (int)min(*cnt, (unsigned)CAP);
  for (int i = blockIdx.x * 256 + threadIdx.x; i < n; i += gridDim.x * 256) {
    const unsigned idx = cidx[i];
    const int l = idx / Sdim;
    const int s = idx - l * Sdim;
    const float c = conf1(csim[i], Rsum[l], Csum[s]);
    cconf[i] = c;
    atomicMaxPosF(&RM[l], c);
    atomicMaxPosF(&CM[s], c);
  }
}

// --- k_final2: final mask over candidates; scatter into zeroed output.
__global__ __launch_bounds__(256)
void k_final2(const unsigned int* __restrict__ cnt, const unsigned int* __restrict__ cidx,
              const float* __restrict__ cconf, const float* __restrict__ RM,
              const float* __restrict__ CM, float* __restrict__ out) {
  const int n = (int)min(*cnt, (unsigned)CAP);
  for (int i = blockIdx.x * 256 + threadIdx.x; i < n; i += gridDim.x * 256) {
    const unsigned idx = cidx[i];
    const int l = idx / Sdim;
    const int s = idx - l * Sdim;
    const float c = cconf[i];
    if (c > THR && valid80(l) && valid80(s) && c == RM[l] && c == CM[s])
      out[idx] = c;
  }
}

}  // namespace

extern "C" void kernel_launch(void* const* d_in, const int* in_sizes, int n_in,
                              void* d_out, int out_size, void* d_ws, size_t ws_size,
                              hipStream_t stream) {
  (void)in_sizes; (void)n_in; (void)out_size; (void)ws_size;
  const float* x0 = reinterpret_cast<const float*>(d_in[0]);
  const float* x1 = reinterpret_cast<const float*>(d_in[1]);
  float* out = reinterpret_cast<float*>(d_out);

  // ws layout: [Rsum 6400][Csum 6400][RM 6400][CM 6400][cnt 4]
  //            [cidx CAP][csim CAP][cconf CAP][XA][XB]
  float* Rsum = reinterpret_cast<float*>(d_ws);
  float* Csum = Rsum + Ldim;
  float* RM = Csum + Sdim;
  float* CM = RM + Ldim;
  unsigned int* cnt = reinterpret_cast<unsigned int*>(CM + Sdim);
  unsigned int* cidx = cnt + 4;
  float* csim = reinterpret_cast<float*>(cidx + CAP);
  float* cconf = csim + CAP;
  unsigned short* XA = reinterpret_cast<unsigned short*>(cconf + CAP);
  const size_t PSZ = (size_t)8 * Ldim * 32;  // ushorts per pre-split buffer
  unsigned short* XB = XA + PSZ;

  // zero stats + count (sums -> 0; RM/CM of positive floats -> 0)
  hipMemsetAsync(d_ws, 0, sizeof(float) * (size_t)(4 * Ldim) + 16, stream);

  k_split<<<Ldim * 32 / 256, 256, 0, stream>>>(x0, XA);
  k_split<<<Ldim * 32 / 256, 256, 0, stream>>>(x1, XB);
  k_gemm_all<<<(Ldim / 128) * (Sdim / 128), 256, 0, stream>>>(
      XA, XB, Rsum, Csum, cnt, cidx, csim);
  hipMemsetAsync(out, 0, sizeof(float) * (size_t)Ldim * Sdim, stream);
  k_final1<<<32, 256, 0, stream>>>(cnt, cidx, csim, Rsum, Csum, RM, CM, cconf);
  k_final2<<<32, 256, 0, stream>>>(cnt, cidx, cconf, RM, CM, out);
}

// Round 7
// 254.514 us; speedup vs baseline: 1.1706x; 1.0794x over previous
//
#include <hip/hip_runtime.h>

namespace {

constexpr int Ldim = 6400;   // rows (h0*w0)
constexpr int Sdim = 6400;   // cols (h1*w1)
constexpr float INV_CT = 0.0390625f;  // 1/(256*0.1), exact
constexpr float THR = 0.2f;
constexpr int CAP = 65536;   // candidate capacity (expected ~0 for this data)

typedef __attribute__((ext_vector_type(8))) short short8;
typedef __attribute__((ext_vector_type(4))) float f32x4;

__device__ __forceinline__ void atomicMaxPosF(float* addr, float v) {
  // valid for non-negative floats: uint bit order == float order
  atomicMax(reinterpret_cast<unsigned int*>(addr), __float_as_uint(v));
}

__device__ __forceinline__ bool valid80(int idx) {
  const int i = idx / 80;
  const int j = idx - i * 80;
  return (i >= 2) & (i < 78) & (j >= 2) & (j < 78);
}

// round-to-nearest-even fp32 -> bf16 bits
__device__ __forceinline__ unsigned short f2bf(float v) {
  unsigned u = __float_as_uint(v);
  return (unsigned short)((u + 0x7fffu + ((u >> 16) & 1u)) >> 16);
}

// The ONE conf expression. Computed exactly once per candidate (k_final1);
// k_final2 reuses the stored value -> == tests bitwise-consistent.
__device__ __forceinline__ float conf1(float s, float rs, float cs) {
  return expf(2.f * s) / (rs * cs);
}

typedef const __attribute__((address_space(1))) unsigned int guint;
typedef __attribute__((address_space(3))) unsigned int suint;
__device__ __forceinline__ void gload16(const void* g, void* l) {
  __builtin_amdgcn_global_load_lds((guint*)g, (suint*)l, 16, 0, 0);
}

// --- P-layout (R3/R4-verified: 0 bank conflicts) ----------------------------
// X' = [kstep 0..7][row 0..6399][granule g' 0..3][8 bf16]  (row block = 64 B)
// slot g' of row r holds k-granule g' ^ ((r>>1)&3).

// merged split: blocks [0,800) do x0 -> XA, blocks [800,1600) do x1 -> XB.
__global__ __launch_bounds__(256)
void k_split2(const float* __restrict__ X0, const float* __restrict__ X1,
              unsigned short* __restrict__ XA, unsigned short* __restrict__ XB) {
  const int half = Ldim * 32 / 256;  // 800 blocks per input
  const bool second = blockIdx.x >= half;
  const float* X = second ? X1 : X0;
  unsigned short* Xh = second ? XB : XA;
  const int g = (blockIdx.x - (second ? half : 0)) * 256 + threadIdx.x;
  const int r = g >> 5;
  const int gt = g & 31;
  const float* src = X + ((size_t)r << 8) + (gt << 3);
  const float4 a = *reinterpret_cast<const float4*>(src);
  const float4 b = *reinterpret_cast<const float4*>(src + 4);
  short8 hv;
  hv[0] = (short)f2bf(a.x); hv[1] = (short)f2bf(a.y);
  hv[2] = (short)f2bf(a.z); hv[3] = (short)f2bf(a.w);
  hv[4] = (short)f2bf(b.x); hv[5] = (short)f2bf(b.y);
  hv[6] = (short)f2bf(b.z); hv[7] = (short)f2bf(b.w);
  const int gp = (gt & 3) ^ ((r >> 1) & 3);
  const size_t dst = ((size_t)((gt >> 2) * Ldim + r) * 4 + gp) << 3;
  *reinterpret_cast<short8*>(Xh + dst) = hv;
}

// --- GEMM main loop (R4 structure: 128x128, BK=32, 4 waves,
//     double-buffered LDS, 2-phase stage-before-compute).
__device__ __forceinline__ void gemm128(
    const unsigned short* __restrict__ A, const unsigned short* __restrict__ B,
    int m0, int n0, int wave, int lane,
    unsigned short (*sA)[4096], unsigned short (*sB)[4096], f32x4 acc[4][4]) {
  const int wr = wave >> 1, wc = wave & 1;
  const int ll = lane & 15;
  const int lg = lane >> 4;
  const int arow = lane >> 2;
  const int gsel = (lane & 3) * 8;

#pragma unroll
  for (int mi = 0; mi < 4; ++mi)
#pragma unroll
    for (int ni = 0; ni < 4; ++ni) acc[mi][ni] = (f32x4){0.f, 0.f, 0.f, 0.f};

  auto stage = [&](int slot, int ks) {
    const size_t kb = (size_t)ks * (Ldim * 32);
#pragma unroll
    for (int p = 0; p < 2; ++p) {
      const int ch = wave * 2 + p;
      const size_t asrc = kb + (size_t)(m0 + ch * 16 + arow) * 32 + gsel;
      const size_t bsrc = kb + (size_t)(n0 + ch * 16 + arow) * 32 + gsel;
      gload16(A + asrc, &sA[slot][ch * 512]);
      gload16(B + bsrc, &sB[slot][ch * 512]);
    }
  };

  stage(0, 0);
  __syncthreads();  // compiler drains vmcnt before s_barrier

  for (int ks = 0; ks < 8; ++ks) {
    const int cur = ks & 1;
    if (ks < 7) stage(cur ^ 1, ks + 1);  // prefetch overlaps this tile's MFMA

    auto rd = [&](unsigned short* S, int row) -> short8 {
      const int gp = lg ^ ((row >> 1) & 3);  // inverse granule swizzle
      return *reinterpret_cast<const short8*>(&S[(row * 4 + gp) * 8]);
    };
    short8 af[4], bfv[4];
#pragma unroll
    for (int mi = 0; mi < 4; ++mi) af[mi] = rd(sA[cur], wr * 64 + mi * 16 + ll);
#pragma unroll
    for (int ni = 0; ni < 4; ++ni) bfv[ni] = rd(sB[cur], wc * 64 + ni * 16 + ll);
#pragma unroll
    for (int mi = 0; mi < 4; ++mi)
#pragma unroll
      for (int ni = 0; ni < 4; ++ni)
        acc[mi][ni] = __builtin_amdgcn_mfma_f32_16x16x32_bf16(af[mi], bfv[ni], acc[mi][ni], 0, 0, 0);

    __syncthreads();  // drains prefetch vmcnt + lgkm before buffer swap
  }

#pragma unroll
  for (int mi = 0; mi < 4; ++mi)
#pragma unroll
    for (int ni = 0; ni < 4; ++ni) acc[mi][ni] *= INV_CT;
}

// --- THE single GEMM pass: zeroes its own output tile (replaces the global
// memset dispatch; stores overlap with MFMA), computes exp-sum stats, and
// extracts candidates via tile-local lower-bound precheck:
//   s > 0.5*(ln(0.18) + ln(Rlow) + ln(Clow))  i.e. e^{2s} > 0.18*Rlow*Clow.
// Over-inclusive for conf>0.2 since Rlow<=Rsum, Clow<=Csum, 0.18<0.2 (11%
// slack >> fp rounding). A row/col whose true max is not a candidate has all
// conf < 0.2 there -> its RM/CM value is irrelevant.
__global__ __launch_bounds__(256)
void k_gemm_all(const unsigned short* __restrict__ A, const unsigned short* __restrict__ B,
                float* __restrict__ Rsum, float* __restrict__ Csum,
                unsigned int* __restrict__ cnt, unsigned int* __restrict__ cidx,
                float* __restrict__ csim, float* __restrict__ out) {
  __shared__ unsigned short sA[2][4096], sB[2][4096];
  const int tid = threadIdx.x;
  const int lane = tid & 63, wave = tid >> 6;
  const int wr = wave >> 1, wc = wave & 1;
  const int ll = lane & 15, lg = lane >> 4;
  const int bx = blockIdx.x % (Sdim / 128);
  const int by = blockIdx.x / (Sdim / 128);
  const int m0 = by * 128, n0 = bx * 128;

  // zero this block's 128x128 output tile (fire-and-forget, overlaps GEMM)
  {
    const float4 z = make_float4(0.f, 0.f, 0.f, 0.f);
#pragma unroll
    for (int i = 0; i < 16; ++i) {
      const int e = i * 256 + tid;   // 0..4095 float4 slots (32 per row)
      const int row = e >> 5;
      const int c4 = e & 31;
      *reinterpret_cast<float4*>(&out[(size_t)(m0 + row) * Sdim + n0 + c4 * 4]) = z;
    }
  }

  f32x4 acc[4][4];
  gemm128(A, B, m0, n0, wave, lane, sA, sB, acc);

  // C/D layout: col = lane&15, row = (lane>>4)*4 + reg  [m89/m91]
  // loop1: exp sums -> atomics; keep per-(mi,r) row sums and per-col sums.
  float re[16];
  float colp[4] = {0.f, 0.f, 0.f, 0.f};
#pragma unroll
  for (int mi = 0; mi < 4; ++mi)
#pragma unroll
    for (int r = 0; r < 4; ++r) {
      float s = 0.f;
#pragma unroll
      for (int ni = 0; ni < 4; ++ni) {
        const float e = expf(acc[mi][ni][r]);
        s += e;
        colp[ni] += e;
      }
      s += __shfl_xor(s, 1);
      s += __shfl_xor(s, 2);
      s += __shfl_xor(s, 4);
      s += __shfl_xor(s, 8);
      re[mi * 4 + r] = s;  // row sum over this wave's 64 cols (all 16 lanes)
      if (ll == 0)
        atomicAdd(&Rsum[m0 + wr * 64 + mi * 16 + lg * 4 + r], s);
    }
  float clw[4];
#pragma unroll
  for (int ni = 0; ni < 4; ++ni) {
    float c = colp[ni];
    c += __shfl_xor(c, 16);
    c += __shfl_xor(c, 32);
    clw[ni] = c;  // col sum over this wave's 64 rows (col = ni*16 + ll)
    if (lane < 16) atomicAdd(&Csum[n0 + wc * 64 + ni * 16 + lane], c);
  }

  // loop2: log-domain precheck, emit candidates (rare).
  constexpr float L018 = -1.7147984f;  // ln(0.18)
  float lc[4];
#pragma unroll
  for (int ni = 0; ni < 4; ++ni) lc[ni] = 0.5f * logf(clw[ni]);
#pragma unroll
  for (int mi = 0; mi < 4; ++mi)
#pragma unroll
    for (int r = 0; r < 4; ++r) {
      const float tr = 0.5f * (L018 + logf(re[mi * 4 + r]));
#pragma unroll
      for (int ni = 0; ni < 4; ++ni) {
        if (acc[mi][ni][r] > tr + lc[ni]) {
          const int row = m0 + wr * 64 + mi * 16 + lg * 4 + r;
          const int col = n0 + wc * 64 + ni * 16 + ll;
          const unsigned t = atomicAdd(cnt, 1u);
          if (t < CAP) {
            cidx[t] = (unsigned)row * Sdim + col;
            csim[t] = acc[mi][ni][r];
          }
        }
      }
    }
}

// --- k_final1: exact conf for each candidate (stored), RM/CM atomicMax.
__global__ __launch_bounds__(256)
void k_final1(const unsigned int* __restrict__ cnt, const unsigned int* __restrict__ cidx,
              const float* __restrict__ csim, const float* __restrict__ Rsum,
              const float* __restrict__ Csum, float* __restrict__ RM,
              float* __restrict__ CM, float* __restrict__ cconf) {
  const int n = (int)min(*cnt, (unsigned)CAP);
  for (int i = blockIdx.x * 256 + threadIdx.x; i < n; i += gridDim.x * 256) {
    const unsigned idx = cidx[i];
    const int l = idx / Sdim;
    const int s = idx - l * Sdim;
    const float c = conf1(csim[i], Rsum[l], Csum[s]);
    cconf[i] = c;
    atomicMaxPosF(&RM[l], c);
    atomicMaxPosF(&CM[s], c);
  }
}

// --- k_final2: final mask over candidates; scatter into zeroed output.
__global__ __launch_bounds__(256)
void k_final2(const unsigned int* __restrict__ cnt, const unsigned int* __restrict__ cidx,
              const float* __restrict__ cconf, const float* __restrict__ RM,
              const float* __restrict__ CM, float* __restrict__ out) {
  const int n = (int)min(*cnt, (unsigned)CAP);
  for (int i = blockIdx.x * 256 + threadIdx.x; i < n; i += gridDim.x * 256) {
    const unsigned idx = cidx[i];
    const int l = idx / Sdim;
    const int s = idx - l * Sdim;
    const float c = cconf[i];
    if (c > THR && valid80(l) && valid80(s) && c == RM[l] && c == CM[s])
      out[idx] = c;
  }
}

}  // namespace

extern "C" void kernel_launch(void* const* d_in, const int* in_sizes, int n_in,
                              void* d_out, int out_size, void* d_ws, size_t ws_size,
                              hipStream_t stream) {
  (void)in_sizes; (void)n_in; (void)out_size; (void)ws_size;
  const float* x0 = reinterpret_cast<const float*>(d_in[0]);
  const float* x1 = reinterpret_cast<const float*>(d_in[1]);
  float* out = reinterpret_cast<float*>(d_out);

  // ws layout: [Rsum 6400][Csum 6400][RM 6400][CM 6400][cnt 4]
  //            [cidx CAP][csim CAP][cconf CAP][XA][XB]
  float* Rsum = reinterpret_cast<float*>(d_ws);
  float* Csum = Rsum + Ldim;
  float* RM = Csum + Sdim;
  float* CM = RM + Ldim;
  unsigned int* cnt = reinterpret_cast<unsigned int*>(CM + Sdim);
  unsigned int* cidx = cnt + 4;
  float* csim = reinterpret_cast<float*>(cidx + CAP);
  float* cconf = csim + CAP;
  unsigned short* XA = reinterpret_cast<unsigned short*>(cconf + CAP);
  const size_t PSZ = (size_t)8 * Ldim * 32;  // ushorts per pre-split buffer
  unsigned short* XB = XA + PSZ;

  // zero stats + count (sums -> 0; RM/CM of positive floats -> 0)
  hipMemsetAsync(d_ws, 0, sizeof(float) * (size_t)(4 * Ldim) + 16, stream);

  k_split2<<<2 * (Ldim * 32 / 256), 256, 0, stream>>>(x0, x1, XA, XB);
  k_gemm_all<<<(Ldim / 128) * (Sdim / 128), 256, 0, stream>>>(
      XA, XB, Rsum, Csum, cnt, cidx, csim, out);
  k_final1<<<32, 256, 0, stream>>>(cnt, cidx, csim, Rsum, Csum, RM, CM, cconf);
  k_final2<<<32, 256, 0, stream>>>(cnt, cidx, cconf, RM, CM, out);
}